// Round 1
// baseline (789.468 us; speedup 1.0000x reference)
//
#include <hip/hip_runtime.h>
#include <math.h>

#define BB 128
#define NN 128
#define DIN 1024
#define H1 256
#define DOUT 32
#define KCL 8
#define NPTS 128
#define MROWS (BB*NN)   // 16384
#define NPAIR (NPTS*(NPTS-1)/2)  // 8128

__device__ __forceinline__ float gelu_exact(float v) {
    return 0.5f * v * (1.0f + erff(v * 0.70710678118654752f));
}

// packed upper-triangle index, i<j, row-major order (== jnp.argmin flat tie-break order)
__device__ __forceinline__ int pidx(int i, int j) {
    return i * 127 - ((i * (i - 1)) >> 1) + (j - i - 1);
}

// ---------------- GEMM1: h = gelu(x) @ W1 + b1  [16384x1024]x[1024x256] ----------------
__global__ __launch_bounds__(256) void mlp1_kernel(const float* __restrict__ x,
                                                   const float* __restrict__ W1,
                                                   const float* __restrict__ b1,
                                                   float* __restrict__ h) {
    __shared__ float As[16][68];  // [k][m], padded stride
    __shared__ float Bs[16][68];  // [k][n]
    const int bm = blockIdx.x;    // 256 row-tiles of 64
    const int bn = blockIdx.y;    // 4 col-tiles of 64
    const int tid = threadIdx.x;
    const int tx = tid & 15, ty = tid >> 4;

    float acc[4][4] = {{0.f}};

    const int arow = tid >> 2;         // 0..63
    const int acol4 = (tid & 3) * 4;   // k offset 0,4,8,12
    const int brow = tid >> 4;         // 0..15 (k)
    const int bcol4 = (tid & 15) * 4;  // 0..60

    const float* xrow = x + (size_t)(bm * 64 + arow) * DIN;

    for (int kt = 0; kt < DIN; kt += 16) {
        float4 av = *(const float4*)(xrow + kt + acol4);
        As[acol4 + 0][arow] = gelu_exact(av.x);
        As[acol4 + 1][arow] = gelu_exact(av.y);
        As[acol4 + 2][arow] = gelu_exact(av.z);
        As[acol4 + 3][arow] = gelu_exact(av.w);
        float4 bv = *(const float4*)(W1 + (size_t)(kt + brow) * H1 + bn * 64 + bcol4);
        *(float4*)&Bs[brow][bcol4] = bv;
        __syncthreads();
#pragma unroll
        for (int kk = 0; kk < 16; ++kk) {
            float4 a = *(const float4*)&As[kk][ty * 4];
            float4 b = *(const float4*)&Bs[kk][tx * 4];
            float ar[4] = {a.x, a.y, a.z, a.w};
            float br[4] = {b.x, b.y, b.z, b.w};
#pragma unroll
            for (int i = 0; i < 4; ++i)
#pragma unroll
                for (int j = 0; j < 4; ++j)
                    acc[i][j] = fmaf(ar[i], br[j], acc[i][j]);
        }
        __syncthreads();
    }

    const int row = bm * 64 + ty * 4;
    const int col = bn * 64 + tx * 4;
    float4 bias = *(const float4*)(b1 + col);
#pragma unroll
    for (int i = 0; i < 4; ++i) {
        float4 o;
        o.x = acc[i][0] + bias.x;
        o.y = acc[i][1] + bias.y;
        o.z = acc[i][2] + bias.z;
        o.w = acc[i][3] + bias.w;
        *(float4*)(h + (size_t)(row + i) * H1 + col) = o;
    }
}

// ---------------- GEMM2: feats = gelu(h) @ W2 + b2  [16384x256]x[256x32] ----------------
__global__ __launch_bounds__(256) void mlp2_kernel(const float* __restrict__ h,
                                                   const float* __restrict__ W2,
                                                   const float* __restrict__ b2,
                                                   float* __restrict__ feats) {
    __shared__ float hs[16][257];       // 16 rows x 256 k, padded
    __shared__ float w2s[H1 * DOUT];    // [k][col] 32 KB
    const int blk = blockIdx.x;         // 1024 blocks, 16 rows each
    const int tid = threadIdx.x;

    for (int i = tid; i < (H1 * DOUT) / 4; i += 256) {
        ((float4*)w2s)[i] = ((const float4*)W2)[i];
    }
    const float* hb = h + (size_t)blk * 16 * H1;
    for (int i = tid; i < (16 * H1) / 4; i += 256) {
        float4 v = ((const float4*)hb)[i];
        int r = i >> 6;           // (i*4)/256
        int c = (i & 63) * 4;
        hs[r][c + 0] = gelu_exact(v.x);
        hs[r][c + 1] = gelu_exact(v.y);
        hs[r][c + 2] = gelu_exact(v.z);
        hs[r][c + 3] = gelu_exact(v.w);
    }
    __syncthreads();

    const int col = tid & 31;
    const int r0 = (tid >> 5) * 2;  // 2 rows per thread
    float acc0 = 0.f, acc1 = 0.f;
    for (int k = 0; k < H1; ++k) {
        float w = w2s[k * DOUT + col];
        acc0 = fmaf(hs[r0 + 0][k], w, acc0);
        acc1 = fmaf(hs[r0 + 1][k], w, acc1);
    }
    float bias = b2[col];
    const int rowg = blk * 16 + r0;
    feats[(size_t)(rowg + 0) * DOUT + col] = acc0 + bias;
    feats[(size_t)(rowg + 1) * DOUT + col] = acc1 + bias;
}

// ---------------- Ward greedy agglomerative clustering, one block per batch ----------------
__global__ __launch_bounds__(256) void ward_kernel(const float* __restrict__ feats,
                                                   int* __restrict__ out) {
    __shared__ float cost[NPAIR];          // packed upper triangle, 32.5 KB
    __shared__ float cents[NPTS * 33];     // padded stride 33 (bank-conflict-free), 16.9 KB
    __shared__ float sq[NPTS];
    __shared__ float szs[NPTS];
    __shared__ int lab[NPTS];
    __shared__ int rnk[NPTS];
    __shared__ float rbv[4];
    __shared__ int rbi[4];
    __shared__ int sel[2];

    const int b = blockIdx.x;
    const int tid = threadIdx.x;

    // load centroids (feats), init sizes/labels
    const float* f = feats + (size_t)b * NPTS * DOUT;
    for (int i = tid; i < NPTS * DOUT; i += 256) {
        int r = i >> 5, d = i & 31;
        cents[r * 33 + d] = f[i];
    }
    if (tid < NPTS) {
        szs[tid] = 1.0f;
        lab[tid] = tid;
    }
    __syncthreads();
    if (tid < NPTS) {
        float s = 0.f;
#pragma unroll
        for (int d = 0; d < 32; ++d) {
            float v = cents[tid * 33 + d];
            s = fmaf(v, v, s);
        }
        sq[tid] = s;
    }
    __syncthreads();
    // initial pair costs (all sizes==1 -> w = 1/(2+1e-30))
    for (int idx = tid; idx < NPTS * NPTS; idx += 256) {
        int i = idx >> 7, j = idx & 127;
        if (i < j) {
            float dot = 0.f;
#pragma unroll
            for (int d = 0; d < 32; ++d)
                dot = fmaf(cents[i * 33 + d], cents[j * 33 + d], dot);
            float d2 = sq[i] + sq[j] - 2.0f * dot;
            if (d2 < 0.f) d2 = 0.f;
            float w = (szs[i] * szs[j]) / (szs[i] + szs[j] + 1e-30f);
            cost[pidx(i, j)] = w * d2;
        }
    }
    __syncthreads();

    for (int it = 0; it < NPTS - KCL; ++it) {
        // ---- argmin over packed costs, first-index tie-break (== jnp.argmin flat order)
        float best = INFINITY;
        int bi = 1 << 30;
        for (int p = tid; p < NPAIR; p += 256) {
            float v = cost[p];
            if (v < best) { best = v; bi = p; }   // ascending p: strict < keeps first
        }
#pragma unroll
        for (int off = 32; off > 0; off >>= 1) {
            float ov = __shfl_down(best, off, 64);
            int oi = __shfl_down(bi, off, 64);
            if (ov < best || (ov == best && oi < bi)) { best = ov; bi = oi; }
        }
        if ((tid & 63) == 0) { rbv[tid >> 6] = best; rbi[tid >> 6] = bi; }
        __syncthreads();
        if (tid == 0) {
            best = rbv[0]; bi = rbi[0];
#pragma unroll
            for (int w = 1; w < 4; ++w) {
                if (rbv[w] < best || (rbv[w] == best && rbi[w] < bi)) { best = rbv[w]; bi = rbi[w]; }
            }
            // decode packed index -> (i,j)
            int p = bi, i = 0;
            while (p >= 127 - i) { p -= 127 - i; ++i; }
            sel[0] = i;
            sel[1] = i + 1 + p;
        }
        __syncthreads();
        const int i2 = sel[0], j2 = sel[1];
        const float si = szs[i2], sj = szs[j2];

        // parallel: label update + invalidate all pairs involving j2; 32 threads update centroid i2
        if (tid < NPTS) {
            if (lab[tid] == j2) lab[tid] = i2;
            if (tid < j2) cost[pidx(tid, j2)] = INFINITY;
            else if (tid > j2) cost[pidx(j2, tid)] = INFINITY;
        }
        if (tid >= 128 && tid < 160) {
            int d = tid - 128;
            cents[i2 * 33 + d] = (cents[i2 * 33 + d] * si + cents[j2 * 33 + d] * sj) / (si + sj);
        }
        __syncthreads();
        if (tid == 0) {
            float s = 0.f;
#pragma unroll
            for (int d = 0; d < 32; ++d) {
                float v = cents[i2 * 33 + d];
                s = fmaf(v, v, s);
            }
            sq[i2] = s;
            szs[i2] = si + sj;
            szs[j2] = 0.f;
        }
        __syncthreads();
        // recompute costs of all active clusters vs merged i2
        if (tid < NPTS) {
            int r = tid;
            if (r != i2 && r != j2 && szs[r] > 0.f) {
                float dot = 0.f;
#pragma unroll
                for (int d = 0; d < 32; ++d)
                    dot = fmaf(cents[r * 33 + d], cents[i2 * 33 + d], dot);
                float d2 = sq[r] + sq[i2] - 2.0f * dot;
                if (d2 < 0.f) d2 = 0.f;
                float w = (szs[r] * szs[i2]) / (szs[r] + szs[i2] + 1e-30f);
                int a = r < i2 ? r : i2;
                int c = r < i2 ? i2 : r;
                cost[pidx(a, c)] = w * d2;
            }
        }
        __syncthreads();
    }

    // relabel survivors to 0..K-1 by index order
    if (tid == 0) {
        int c = 0;
        for (int i = 0; i < NPTS; ++i) rnk[i] = (szs[i] > 0.f) ? c++ : -1;
    }
    __syncthreads();
    if (tid < NPTS) out[b * NPTS + tid] = rnk[lab[tid]];
}

extern "C" void kernel_launch(void* const* d_in, const int* in_sizes, int n_in,
                              void* d_out, int out_size, void* d_ws, size_t ws_size,
                              hipStream_t stream) {
    const float* x  = (const float*)d_in[0];
    const float* W1 = (const float*)d_in[1];
    const float* b1 = (const float*)d_in[2];
    const float* W2 = (const float*)d_in[3];
    const float* b2 = (const float*)d_in[4];

    float* h = (float*)d_ws;                       // 16384*256 f32 = 16 MB
    float* feats = h + (size_t)MROWS * H1;         // 16384*32 f32 = 2 MB
    int* out = (int*)d_out;

    mlp1_kernel<<<dim3(MROWS / 64, H1 / 64), 256, 0, stream>>>(x, W1, b1, h);
    mlp2_kernel<<<MROWS / 16, 256, 0, stream>>>(h, W2, b2, feats);
    ward_kernel<<<BB, 256, 0, stream>>>(feats, out);
}

// Round 2
// 706.764 us; speedup vs baseline: 1.1170x; 1.1170x over previous
//
#include <hip/hip_runtime.h>
#include <math.h>

#define BB 128
#define NN 128
#define DIN 1024
#define H1 256
#define DOUT 32
#define KCL 8
#define NPTS 128
#define MROWS (BB*NN)   // 16384
#define NPAIR (NPTS*(NPTS-1)/2)  // 8128
#define CSTRIDE 129
#define DEADKEY 0xFFFFFFFF00000000ull

__device__ __forceinline__ float gelu_exact(float v) {
    return 0.5f * v * (1.0f + erff(v * 0.70710678118654752f));
}

// packed upper-triangle index, i<j, row-major order (== jnp.argmin flat tie-break order)
__device__ __forceinline__ int pidx(int i, int j) {
    return i * 127 - ((i * (i - 1)) >> 1) + (j - i - 1);
}

// single-wave "barrier": drain LDS ops + compiler memory fence
__device__ __forceinline__ void wbar() {
    __asm__ volatile("s_waitcnt lgkmcnt(0)" ::: "memory");
}

__device__ __forceinline__ unsigned long long mkkey(float v, int r, int j) {
    return ((unsigned long long)__float_as_uint(v) << 32) | (unsigned)((r << 7) | j);
}

// ---------------- GEMM1: h = gelu(x) @ W1 + b1  [16384x1024]x[1024x256] ----------------
__global__ __launch_bounds__(256) void mlp1_kernel(const float* __restrict__ x,
                                                   const float* __restrict__ W1,
                                                   const float* __restrict__ b1,
                                                   float* __restrict__ h) {
    __shared__ float As[16][68];  // [k][m], padded stride
    __shared__ float Bs[16][68];  // [k][n]
    const int bm = blockIdx.x;    // 256 row-tiles of 64
    const int bn = blockIdx.y;    // 4 col-tiles of 64
    const int tid = threadIdx.x;
    const int tx = tid & 15, ty = tid >> 4;

    float acc[4][4] = {{0.f}};

    const int arow = tid >> 2;         // 0..63
    const int acol4 = (tid & 3) * 4;   // k offset 0,4,8,12
    const int brow = tid >> 4;         // 0..15 (k)
    const int bcol4 = (tid & 15) * 4;  // 0..60

    const float* xrow = x + (size_t)(bm * 64 + arow) * DIN;

    for (int kt = 0; kt < DIN; kt += 16) {
        float4 av = *(const float4*)(xrow + kt + acol4);
        As[acol4 + 0][arow] = gelu_exact(av.x);
        As[acol4 + 1][arow] = gelu_exact(av.y);
        As[acol4 + 2][arow] = gelu_exact(av.z);
        As[acol4 + 3][arow] = gelu_exact(av.w);
        float4 bv = *(const float4*)(W1 + (size_t)(kt + brow) * H1 + bn * 64 + bcol4);
        *(float4*)&Bs[brow][bcol4] = bv;
        __syncthreads();
#pragma unroll
        for (int kk = 0; kk < 16; ++kk) {
            float4 a = *(const float4*)&As[kk][ty * 4];
            float4 b = *(const float4*)&Bs[kk][tx * 4];
            float ar[4] = {a.x, a.y, a.z, a.w};
            float br[4] = {b.x, b.y, b.z, b.w};
#pragma unroll
            for (int i = 0; i < 4; ++i)
#pragma unroll
                for (int j = 0; j < 4; ++j)
                    acc[i][j] = fmaf(ar[i], br[j], acc[i][j]);
        }
        __syncthreads();
    }

    const int row = bm * 64 + ty * 4;
    const int col = bn * 64 + tx * 4;
    float4 bias = *(const float4*)(b1 + col);
#pragma unroll
    for (int i = 0; i < 4; ++i) {
        float4 o;
        o.x = acc[i][0] + bias.x;
        o.y = acc[i][1] + bias.y;
        o.z = acc[i][2] + bias.z;
        o.w = acc[i][3] + bias.w;
        *(float4*)(h + (size_t)(row + i) * H1 + col) = o;
    }
}

// ---------------- GEMM2: feats = gelu(h) @ W2 + b2  [16384x256]x[256x32] ----------------
__global__ __launch_bounds__(256) void mlp2_kernel(const float* __restrict__ h,
                                                   const float* __restrict__ W2,
                                                   const float* __restrict__ b2,
                                                   float* __restrict__ feats) {
    __shared__ float hs[16][257];       // 16 rows x 256 k, padded
    __shared__ float w2s[H1 * DOUT];    // [k][col] 32 KB
    const int blk = blockIdx.x;         // 1024 blocks, 16 rows each
    const int tid = threadIdx.x;

    for (int i = tid; i < (H1 * DOUT) / 4; i += 256) {
        ((float4*)w2s)[i] = ((const float4*)W2)[i];
    }
    const float* hb = h + (size_t)blk * 16 * H1;
    for (int i = tid; i < (16 * H1) / 4; i += 256) {
        float4 v = ((const float4*)hb)[i];
        int r = i >> 6;           // (i*4)/256
        int c = (i & 63) * 4;
        hs[r][c + 0] = gelu_exact(v.x);
        hs[r][c + 1] = gelu_exact(v.y);
        hs[r][c + 2] = gelu_exact(v.z);
        hs[r][c + 3] = gelu_exact(v.w);
    }
    __syncthreads();

    const int col = tid & 31;
    const int r0 = (tid >> 5) * 2;  // 2 rows per thread
    float acc0 = 0.f, acc1 = 0.f;
    for (int k = 0; k < H1; ++k) {
        float w = w2s[k * DOUT + col];
        acc0 = fmaf(hs[r0 + 0][k], w, acc0);
        acc1 = fmaf(hs[r0 + 1][k], w, acc1);
    }
    float bias = b2[col];
    const int rowg = blk * 16 + r0;
    feats[(size_t)(rowg + 0) * DOUT + col] = acc0 + bias;
    feats[(size_t)(rowg + 1) * DOUT + col] = acc1 + bias;
}

// ---------------- Ward clustering: rowmin-cached, single-wave iterations ----------------
__device__ __forceinline__ void rescan_row(float* cost, unsigned long long* rowkey,
                                           int r, int lane) {
    unsigned long long best = DEADKEY;
    const int L = 127 - r;
    const int base = (L > 0) ? pidx(r, r + 1) : 0;
    if (lane < L) {
        float v = cost[base + lane];
        best = mkkey(v, r, r + 1 + lane);
    }
    int t2 = lane + 64;
    if (t2 < L) {
        float v = cost[base + t2];
        unsigned long long k = mkkey(v, r, r + 1 + t2);
        if (k < best) best = k;
    }
#pragma unroll
    for (int off = 32; off > 0; off >>= 1) {
        unsigned long long o = __shfl_down(best, off, 64);
        if (o < best) best = o;
    }
    if (lane == 0) rowkey[r] = best;
}

__global__ __launch_bounds__(256) void ward_kernel(const float* __restrict__ feats,
                                                   int* __restrict__ out) {
    __shared__ float cost[NPAIR];                 // 32.5 KB
    __shared__ float centsT[32 * CSTRIDE];        // transposed [d][r], 16.5 KB
    __shared__ unsigned long long rowkey[NPTS];   // 1 KB
    __shared__ float sq[NPTS];
    __shared__ float szs[NPTS];
    __shared__ int lab[NPTS];
    __shared__ int rnk[NPTS];

    const int b = blockIdx.x;
    const int tid = threadIdx.x;
    const float* f = feats + (size_t)b * NPTS * DOUT;

    // ---- init (all 4 waves) ----
    for (int i = tid; i < NPTS * DOUT; i += 256) {
        int r = i >> 5, d = i & 31;
        centsT[d * CSTRIDE + r] = f[i];
    }
    if (tid < NPTS) { szs[tid] = 1.0f; lab[tid] = tid; }
    __syncthreads();
    if (tid < NPTS) {
        float s = 0.f;
#pragma unroll
        for (int d = 0; d < 32; ++d) {
            float v = centsT[d * CSTRIDE + tid];
            s = fmaf(v, v, s);
        }
        sq[tid] = s;
    }
    __syncthreads();
    // initial pair costs via 8x8 register Gram tiles (16x16 thread grid, upper-tri tiles)
    {
        int ti = tid >> 4, tj = tid & 15;
        if (tj >= ti) {
            int I0 = ti * 8, J0 = tj * 8;
            float acc[8][8];
#pragma unroll
            for (int u = 0; u < 8; ++u)
#pragma unroll
                for (int v = 0; v < 8; ++v) acc[u][v] = 0.f;
            for (int d = 0; d < 32; ++d) {
                float a[8], bb[8];
#pragma unroll
                for (int u = 0; u < 8; ++u) a[u] = centsT[d * CSTRIDE + I0 + u];
#pragma unroll
                for (int v = 0; v < 8; ++v) bb[v] = centsT[d * CSTRIDE + J0 + v];
#pragma unroll
                for (int u = 0; u < 8; ++u)
#pragma unroll
                    for (int v = 0; v < 8; ++v)
                        acc[u][v] = fmaf(a[u], bb[v], acc[u][v]);
            }
#pragma unroll
            for (int u = 0; u < 8; ++u) {
#pragma unroll
                for (int v = 0; v < 8; ++v) {
                    int i = I0 + u, j = J0 + v;
                    if (i < j) {
                        float d2 = sq[i] + sq[j] - 2.0f * acc[u][v];
                        if (d2 < 0.f) d2 = 0.f;
                        float w = (szs[i] * szs[j]) / (szs[i] + szs[j] + 1e-30f);
                        cost[pidx(i, j)] = w * d2;
                    }
                }
            }
        }
    }
    __syncthreads();
    // initial rowkeys
    if (tid < NPTS) {
        int r = tid;
        unsigned long long best = DEADKEY;
        int L = 127 - r;
        int base = (L > 0) ? pidx(r, r + 1) : 0;
        for (int t = 0; t < L; ++t) {
            float v = cost[base + t];
            unsigned long long k = mkkey(v, r, r + 1 + t);
            if (k < best) best = k;
        }
        rowkey[r] = best;
    }
    __syncthreads();

    if (tid >= 64) return;  // waves 1..3 done; wave 0 runs the merge loop barrier-free
    const int lane = tid;
    const int r0 = lane * 2, r1 = lane * 2 + 1;

    for (int it = 0; it < NPTS - KCL; ++it) {
        // 1) global argmin over 128 cached row keys
        unsigned long long k0 = rowkey[r0], k1 = rowkey[r1];
        unsigned long long best = k0 < k1 ? k0 : k1;
#pragma unroll
        for (int off = 32; off > 0; off >>= 1) {
            unsigned long long o = __shfl_down(best, off, 64);
            if (o < best) best = o;
        }
        best = __shfl(best, 0, 64);
        const int i2 = (int)((best >> 7) & 127u);
        const int j2 = (int)(best & 127u);
        const float si = szs[i2], sj = szs[j2];
        const float snew = si + sj;

        // dirty rows: cached argmin pointed at i2 or j2 (read BEFORE any rowkey/szs writes)
        float s0 = szs[r0], s1 = szs[r1];
        int arg0 = (int)(k0 & 127u), arg1 = (int)(k1 & 127u);
        bool d0 = (s0 > 0.f) && r0 != i2 && r0 != j2 && (arg0 == i2 || arg0 == j2);
        bool d1 = (s1 > 0.f) && r1 != i2 && r1 != j2 && (arg1 == i2 || arg1 == j2);
        unsigned long long m0 = __ballot(d0), m1 = __ballot(d1);

        // 2) centroid merge (32 lanes), invalidate pairs with j2, labels
        if (lane < 32) {
            float ci = centsT[lane * CSTRIDE + i2];
            float cj = centsT[lane * CSTRIDE + j2];
            centsT[lane * CSTRIDE + i2] = (ci * si + cj * sj) / (si + sj);
        }
        if (r0 != j2) { if (r0 < j2) cost[pidx(r0, j2)] = INFINITY; else cost[pidx(j2, r0)] = INFINITY; }
        if (r1 != j2) { if (r1 < j2) cost[pidx(r1, j2)] = INFINITY; else cost[pidx(j2, r1)] = INFINITY; }
        if (lab[r0] == j2) lab[r0] = i2;
        if (lab[r1] == j2) lab[r1] = i2;
        wbar();

        // 3) sq[i2] (sequential fma chain — same order as reference-passing version), sizes
        if (lane == 0) {
            float s = 0.f;
#pragma unroll
            for (int d = 0; d < 32; ++d) {
                float v = centsT[d * CSTRIDE + i2];
                s = fmaf(v, v, s);
            }
            sq[i2] = s;
            szs[i2] = snew;
            szs[j2] = 0.f;
            rowkey[j2] = DEADKEY;
        }
        wbar();

        // 4) recompute costs of active rows vs merged i2 (2 rows/lane, shared broadcast of i2)
        bool w0 = (szs[r0] > 0.f) && r0 != i2 && r0 != j2;
        bool w1 = (szs[r1] > 0.f) && r1 != i2 && r1 != j2;
        if (w0 | w1) {
            float dot0 = 0.f, dot1 = 0.f;
#pragma unroll
            for (int d = 0; d < 32; ++d) {
                float c2 = centsT[d * CSTRIDE + i2];
                dot0 = fmaf(centsT[d * CSTRIDE + r0], c2, dot0);
                dot1 = fmaf(centsT[d * CSTRIDE + r1], c2, dot1);
            }
            float sqi2 = sq[i2];
            if (w0) {
                float d2 = sq[r0] + sqi2 - 2.0f * dot0;
                if (d2 < 0.f) d2 = 0.f;
                float w = (szs[r0] * snew) / (szs[r0] + snew + 1e-30f);
                float v0 = w * d2;
                int a = r0 < i2 ? r0 : i2, c = r0 < i2 ? i2 : r0;
                cost[pidx(a, c)] = v0;
                if (r0 < i2 && !d0) {
                    unsigned long long nk = mkkey(v0, r0, i2);
                    if (nk < k0) rowkey[r0] = nk;
                }
            }
            if (w1) {
                float d2 = sq[r1] + sqi2 - 2.0f * dot1;
                if (d2 < 0.f) d2 = 0.f;
                float w = (szs[r1] * snew) / (szs[r1] + snew + 1e-30f);
                float v1 = w * d2;
                int a = r1 < i2 ? r1 : i2, c = r1 < i2 ? i2 : r1;
                cost[pidx(a, c)] = v1;
                if (r1 < i2 && !d1) {
                    unsigned long long nk = mkkey(v1, r1, i2);
                    if (nk < k1) rowkey[r1] = nk;
                }
            }
        }
        wbar();

        // 5) rescans: row i2 (always changed) + dirty rows
        rescan_row(cost, rowkey, i2, lane);
        unsigned long long mm0 = m0, mm1 = m1;
        while (mm0 | mm1) {
            int r;
            if (mm0) { int bb = __ffsll((unsigned long long)mm0) - 1; r = 2 * bb; mm0 &= mm0 - 1; }
            else     { int bb = __ffsll((unsigned long long)mm1) - 1; r = 2 * bb + 1; mm1 &= mm1 - 1; }
            rescan_row(cost, rowkey, r, lane);
        }
        wbar();
    }

    // relabel survivors to 0..K-1 by index order
    if (lane == 0) {
        int c = 0;
        for (int i = 0; i < NPTS; ++i) rnk[i] = (szs[i] > 0.f) ? c++ : -1;
    }
    wbar();
    out[b * NPTS + r0] = rnk[lab[r0]];
    out[b * NPTS + r1] = rnk[lab[r1]];
}

extern "C" void kernel_launch(void* const* d_in, const int* in_sizes, int n_in,
                              void* d_out, int out_size, void* d_ws, size_t ws_size,
                              hipStream_t stream) {
    const float* x  = (const float*)d_in[0];
    const float* W1 = (const float*)d_in[1];
    const float* b1 = (const float*)d_in[2];
    const float* W2 = (const float*)d_in[3];
    const float* b2 = (const float*)d_in[4];

    float* h = (float*)d_ws;                       // 16384*256 f32 = 16 MB
    float* feats = h + (size_t)MROWS * H1;         // 16384*32 f32 = 2 MB
    int* out = (int*)d_out;

    mlp1_kernel<<<dim3(MROWS / 64, H1 / 64), 256, 0, stream>>>(x, W1, b1, h);
    mlp2_kernel<<<MROWS / 16, 256, 0, stream>>>(h, W2, b2, feats);
    ward_kernel<<<BB, 256, 0, stream>>>(feats, out);
}

// Round 3
// 612.487 us; speedup vs baseline: 1.2890x; 1.1539x over previous
//
#include <hip/hip_runtime.h>
#include <math.h>

#define BB 128
#define NN 128
#define DIN 1024
#define H1 256
#define DOUT 32
#define KCL 8
#define NPTS 128
#define MROWS (BB*NN)   // 16384
#define NPAIR (NPTS*(NPTS-1)/2)  // 8128
#define CSTRIDE 130
#define DEADKEY 0xFFFFFFFF00000000ull

__device__ __forceinline__ float gelu_exact(float v) {
    return 0.5f * v * (1.0f + erff(v * 0.70710678118654752f));
}

// packed upper-triangle index, i<j, row-major order (== jnp.argmin flat tie-break order)
__device__ __forceinline__ int pidx(int i, int j) {
    return i * 127 - ((i * (i - 1)) >> 1) + (j - i - 1);
}

// single-wave "barrier": drain LDS ops + compiler memory fence
__device__ __forceinline__ void wbar() {
    __asm__ volatile("s_waitcnt lgkmcnt(0)" ::: "memory");
}

__device__ __forceinline__ unsigned long long mkkey(float v, int r, int j) {
    return ((unsigned long long)__float_as_uint(v) << 32) | (unsigned)((r << 7) | j);
}

// ---- DPP u64 min step: k = min(k, dpp_shift(k)); invalid/unmasked lanes keep old (=self)
template<int CTRL, int RMASK>
__device__ __forceinline__ unsigned long long dpp_min_step(unsigned long long k) {
    unsigned lo = (unsigned)k, hi = (unsigned)(k >> 32);
    unsigned tlo = (unsigned)__builtin_amdgcn_update_dpp((int)lo, (int)lo, CTRL, RMASK, 0xf, false);
    unsigned thi = (unsigned)__builtin_amdgcn_update_dpp((int)hi, (int)hi, CTRL, RMASK, 0xf, false);
    unsigned long long t = ((unsigned long long)thi << 32) | tlo;
    return t < k ? t : k;
}

__device__ __forceinline__ unsigned long long read64(unsigned long long k, int lane) {
    unsigned lo = (unsigned)__builtin_amdgcn_readlane((int)(unsigned)k, lane);
    unsigned hi = (unsigned)__builtin_amdgcn_readlane((int)(k >> 32), lane);
    return ((unsigned long long)hi << 32) | lo;
}

// full-wave u64 min, result broadcast to all lanes (VALU DPP chain, no LDS)
__device__ __forceinline__ unsigned long long wave_min64(unsigned long long k) {
    k = dpp_min_step<0x111, 0xf>(k);  // row_shr:1
    k = dpp_min_step<0x112, 0xf>(k);  // row_shr:2
    k = dpp_min_step<0x114, 0xf>(k);  // row_shr:4
    k = dpp_min_step<0x118, 0xf>(k);  // row_shr:8  -> lane15 of each row has row-min
    k = dpp_min_step<0x142, 0xa>(k);  // row_bcast15 into rows 1,3 -> lane31: min(0..31), lane63: min(32..63)
    k = dpp_min_step<0x143, 0xc>(k);  // row_bcast31 into rows 2,3 -> lane63: min(0..63)
    return read64(k, 63);
}

// dual 32-lane u64 min: after call lane31 = min(lanes0..31), lane63 = min(lanes32..63)
__device__ __forceinline__ unsigned long long half_min64(unsigned long long k) {
    k = dpp_min_step<0x111, 0xf>(k);
    k = dpp_min_step<0x112, 0xf>(k);
    k = dpp_min_step<0x114, 0xf>(k);
    k = dpp_min_step<0x118, 0xf>(k);
    k = dpp_min_step<0x142, 0xa>(k);
    return k;
}

// ---------------- GEMM1: h = gelu(x) @ W1 + b1  [16384x1024]x[1024x256] ----------------
// 128x128 block tile, 8x8 per-thread accum, BK=16. Per-output fma chain is ascending k
// (identical rounding to the validated 64x64 version).
__global__ __launch_bounds__(256) void mlp1_kernel(const float* __restrict__ x,
                                                   const float* __restrict__ W1,
                                                   const float* __restrict__ b1,
                                                   float* __restrict__ h) {
    __shared__ float As[16][132];  // [k][m]
    __shared__ float Bs[16][132];  // [k][n]
    const int bm = blockIdx.x;    // 128 row-tiles
    const int bn = blockIdx.y;    // 2 col-tiles
    const int tid = threadIdx.x;
    const int tx = tid & 15, ty = tid >> 4;

    float acc[8][8];
#pragma unroll
    for (int i = 0; i < 8; ++i)
#pragma unroll
        for (int j = 0; j < 8; ++j) acc[i][j] = 0.f;

    const int ar0 = tid >> 2;           // 0..63 (rows ar0, ar0+64)
    const int aq0 = (tid & 3) * 4;      // k offset 0,4,8,12
    const int bk0 = tid >> 5;           // 0..7 (k rows bk0, bk0+8)
    const int bn0 = (tid & 31) * 4;     // 0..124

    const float* xbase = x + (size_t)(bm * 128) * DIN;
    const float* wbase = W1 + bn * 128;

    for (int kt = 0; kt < DIN; kt += 16) {
        float4 a0 = *(const float4*)(xbase + (size_t)ar0 * DIN + kt + aq0);
        float4 a1 = *(const float4*)(xbase + (size_t)(ar0 + 64) * DIN + kt + aq0);
        float4 w0 = *(const float4*)(wbase + (size_t)(kt + bk0) * H1 + bn0);
        float4 w1 = *(const float4*)(wbase + (size_t)(kt + bk0 + 8) * H1 + bn0);
        __syncthreads();
        As[aq0 + 0][ar0] = gelu_exact(a0.x);
        As[aq0 + 1][ar0] = gelu_exact(a0.y);
        As[aq0 + 2][ar0] = gelu_exact(a0.z);
        As[aq0 + 3][ar0] = gelu_exact(a0.w);
        As[aq0 + 0][ar0 + 64] = gelu_exact(a1.x);
        As[aq0 + 1][ar0 + 64] = gelu_exact(a1.y);
        As[aq0 + 2][ar0 + 64] = gelu_exact(a1.z);
        As[aq0 + 3][ar0 + 64] = gelu_exact(a1.w);
        *(float4*)&Bs[bk0][bn0] = w0;
        *(float4*)&Bs[bk0 + 8][bn0] = w1;
        __syncthreads();
#pragma unroll
        for (int kk = 0; kk < 16; ++kk) {
            float a[8], b[8];
            *(float4*)&a[0] = *(const float4*)&As[kk][ty * 8];
            *(float4*)&a[4] = *(const float4*)&As[kk][ty * 8 + 4];
            *(float4*)&b[0] = *(const float4*)&Bs[kk][tx * 8];
            *(float4*)&b[4] = *(const float4*)&Bs[kk][tx * 8 + 4];
#pragma unroll
            for (int i = 0; i < 8; ++i)
#pragma unroll
                for (int j = 0; j < 8; ++j)
                    acc[i][j] = fmaf(a[i], b[j], acc[i][j]);
        }
    }

    const int row = bm * 128 + ty * 8;
    const int col = bn * 128 + tx * 8;
    float bias[8];
    *(float4*)&bias[0] = *(const float4*)(b1 + col);
    *(float4*)&bias[4] = *(const float4*)(b1 + col + 4);
#pragma unroll
    for (int i = 0; i < 8; ++i) {
        float o[8];
#pragma unroll
        for (int j = 0; j < 8; ++j) o[j] = acc[i][j] + bias[j];
        *(float4*)(h + (size_t)(row + i) * H1 + col) = *(float4*)&o[0];
        *(float4*)(h + (size_t)(row + i) * H1 + col + 4) = *(float4*)&o[4];
    }
}

// ---------------- GEMM2: feats = gelu(h) @ W2 + b2  [16384x256]x[256x32] ----------------
__global__ __launch_bounds__(256) void mlp2_kernel(const float* __restrict__ h,
                                                   const float* __restrict__ W2,
                                                   const float* __restrict__ b2,
                                                   float* __restrict__ feats) {
    __shared__ float hs[16][257];
    __shared__ float w2s[H1 * DOUT];
    const int blk = blockIdx.x;
    const int tid = threadIdx.x;

    for (int i = tid; i < (H1 * DOUT) / 4; i += 256) {
        ((float4*)w2s)[i] = ((const float4*)W2)[i];
    }
    const float* hb = h + (size_t)blk * 16 * H1;
    for (int i = tid; i < (16 * H1) / 4; i += 256) {
        float4 v = ((const float4*)hb)[i];
        int r = i >> 6;
        int c = (i & 63) * 4;
        hs[r][c + 0] = gelu_exact(v.x);
        hs[r][c + 1] = gelu_exact(v.y);
        hs[r][c + 2] = gelu_exact(v.z);
        hs[r][c + 3] = gelu_exact(v.w);
    }
    __syncthreads();

    const int col = tid & 31;
    const int r0 = (tid >> 5) * 2;
    float acc0 = 0.f, acc1 = 0.f;
    for (int k = 0; k < H1; ++k) {
        float w = w2s[k * DOUT + col];
        acc0 = fmaf(hs[r0 + 0][k], w, acc0);
        acc1 = fmaf(hs[r0 + 1][k], w, acc1);
    }
    float bias = b2[col];
    const int rowg = blk * 16 + r0;
    feats[(size_t)(rowg + 0) * DOUT + col] = acc0 + bias;
    feats[(size_t)(rowg + 1) * DOUT + col] = acc1 + bias;
}

// ---------------- Ward clustering: register state + DPP reductions, single wave ----------------
__global__ __launch_bounds__(256) void ward_kernel(const float* __restrict__ feats,
                                                   int* __restrict__ out) {
    __shared__ float cost[NPAIR];                 // 32.5 KB
    __shared__ float centsT[32 * CSTRIDE];        // [d][r], stride 130 (b64-aligned own-row reads)
    __shared__ unsigned long long rowkey[NPTS];   // init handoff only
    __shared__ float sqArr[NPTS];                 // init handoff only
    __shared__ float szsE[NPTS];                  // final relabel
    __shared__ int rnk[NPTS];

    const int b = blockIdx.x;
    const int tid = threadIdx.x;
    const float* f = feats + (size_t)b * NPTS * DOUT;

    // ---- init (all 4 waves) ----
    for (int i = tid; i < NPTS * DOUT; i += 256) {
        int r = i >> 5, d = i & 31;
        centsT[d * CSTRIDE + r] = f[i];
    }
    __syncthreads();
    if (tid < NPTS) {
        float s = 0.f;
#pragma unroll
        for (int d = 0; d < 32; ++d) {
            float v = centsT[d * CSTRIDE + tid];
            s = fmaf(v, v, s);
        }
        sqArr[tid] = s;
    }
    __syncthreads();
    // initial pair costs via 8x8 register Gram tiles (all sizes are 1.0f)
    {
        int ti = tid >> 4, tj = tid & 15;
        if (tj >= ti) {
            int I0 = ti * 8, J0 = tj * 8;
            float acc[8][8];
#pragma unroll
            for (int u = 0; u < 8; ++u)
#pragma unroll
                for (int v = 0; v < 8; ++v) acc[u][v] = 0.f;
            for (int d = 0; d < 32; ++d) {
                float a[8], bb[8];
#pragma unroll
                for (int u = 0; u < 8; ++u) a[u] = centsT[d * CSTRIDE + I0 + u];
#pragma unroll
                for (int v = 0; v < 8; ++v) bb[v] = centsT[d * CSTRIDE + J0 + v];
#pragma unroll
                for (int u = 0; u < 8; ++u)
#pragma unroll
                    for (int v = 0; v < 8; ++v)
                        acc[u][v] = fmaf(a[u], bb[v], acc[u][v]);
            }
#pragma unroll
            for (int u = 0; u < 8; ++u) {
#pragma unroll
                for (int v = 0; v < 8; ++v) {
                    int i = I0 + u, j = J0 + v;
                    if (i < j) {
                        float d2 = sqArr[i] + sqArr[j] - 2.0f * acc[u][v];
                        if (d2 < 0.f) d2 = 0.f;
                        float w = (1.0f * 1.0f) / (1.0f + 1.0f + 1e-30f);
                        cost[pidx(i, j)] = w * d2;
                    }
                }
            }
        }
    }
    __syncthreads();
    // initial rowkeys
    if (tid < NPTS) {
        int r = tid;
        unsigned long long best = DEADKEY;
        int L = 127 - r;
        int base = (L > 0) ? pidx(r, r + 1) : 0;
        for (int t = 0; t < L; ++t) {
            float v = cost[base + t];
            unsigned long long k = mkkey(v, r, r + 1 + t);
            if (k < best) best = k;
        }
        rowkey[r] = best;
    }
    __syncthreads();

    if (tid >= 64) return;  // wave 0 runs the merge loop; no __syncthreads below
    const int lane = tid;
    const int r0 = lane * 2, r1 = lane * 2 + 1;

    // per-lane register state for rows r0, r1
    unsigned long long k0 = rowkey[r0], k1 = rowkey[r1];
    float q0 = sqArr[r0], q1 = sqArr[r1];
    float s0 = 1.0f, s1 = 1.0f;
    int lab0 = r0, lab1 = r1;
    wbar();

    for (int it = 0; it < NPTS - KCL; ++it) {
        // P1: global argmin over 128 row keys (pure VALU/DPP)
        unsigned long long kmin = k0 < k1 ? k0 : k1;
        kmin = wave_min64(kmin);
        const int i2 = (int)((kmin >> 7) & 127u);
        const int j2 = (int)(kmin & 127u);

        // sizes of i2/j2 via readlane (scalar broadcast)
        float candi = (i2 & 1) ? s1 : s0;
        float candj = (j2 & 1) ? s1 : s0;
        float si = __int_as_float(__builtin_amdgcn_readlane(__float_as_int(candi), i2 >> 1));
        float sj = __int_as_float(__builtin_amdgcn_readlane(__float_as_int(candj), j2 >> 1));
        const float snew = si + sj;

        // dirty rows (args read from OLD keys, sizes pre-update)
        int arg0 = (int)(k0 & 127u), arg1 = (int)(k1 & 127u);
        bool d0 = (s0 > 0.f) && r0 != i2 && r0 != j2 && (arg0 == i2 || arg0 == j2);
        bool d1 = (s1 > 0.f) && r1 != i2 && r1 != j2 && (arg1 == i2 || arg1 == j2);
        unsigned long long m0 = __ballot(d0), m1 = __ballot(d1);

        // P3: centroid merge (lanes<32), invalidate pairs with j2, register state updates
        if (lane < 32) {
            float ci = centsT[lane * CSTRIDE + i2];
            float cj = centsT[lane * CSTRIDE + j2];
            centsT[lane * CSTRIDE + i2] = (ci * si + cj * sj) / (si + sj);
        }
        if (r0 != j2) { cost[r0 < j2 ? pidx(r0, j2) : pidx(j2, r0)] = INFINITY; }
        if (r1 != j2) { cost[r1 < j2 ? pidx(r1, j2) : pidx(j2, r1)] = INFINITY; }
        if (lab0 == j2) lab0 = i2;
        if (lab1 == j2) lab1 = i2;
        if (r0 == i2) s0 = snew; else if (r0 == j2) { s0 = 0.f; k0 = DEADKEY; }
        if (r1 == i2) s1 = snew; else if (r1 == j2) { s1 = 0.f; k1 = DEADKEY; }
        wbar();

        // P4/P5 fused: sq(merged) chain + dots + cost writes + opportunistic key updates
        float qn = 0.f, dot0 = 0.f, dot1 = 0.f;
#pragma unroll
        for (int d = 0; d < 32; ++d) {
            float c2 = centsT[d * CSTRIDE + i2];                       // broadcast
            float2 ow = *(const float2*)&centsT[d * CSTRIDE + r0];     // own rows via b64
            qn = fmaf(c2, c2, qn);
            dot0 = fmaf(ow.x, c2, dot0);
            dot1 = fmaf(ow.y, c2, dot1);
        }
        if (r0 == i2) q0 = qn;
        if (r1 == i2) q1 = qn;
        bool w0 = (s0 > 0.f) && r0 != i2 && r0 != j2;
        bool w1 = (s1 > 0.f) && r1 != i2 && r1 != j2;
        if (w0) {
            float d2 = q0 + qn - 2.0f * dot0;
            if (d2 < 0.f) d2 = 0.f;
            float w = (s0 * snew) / (s0 + snew + 1e-30f);
            float v0 = w * d2;
            cost[r0 < i2 ? pidx(r0, i2) : pidx(i2, r0)] = v0;
            if (r0 < i2 && !d0) {
                unsigned long long nk = mkkey(v0, r0, i2);
                if (nk < k0) k0 = nk;
            }
        }
        if (w1) {
            float d2 = q1 + qn - 2.0f * dot1;
            if (d2 < 0.f) d2 = 0.f;
            float w = (s1 * snew) / (s1 + snew + 1e-30f);
            float v1 = w * d2;
            cost[r1 < i2 ? pidx(r1, i2) : pidx(i2, r1)] = v1;
            if (r1 < i2 && !d1) {
                unsigned long long nk = mkkey(v1, r1, i2);
                if (nk < k1) k1 = nk;
            }
        }
        wbar();

        // P6: rescans (row i2 + dirty rows), 2 rows per round via half-wave DPP reduces
        bool pi = true;
        unsigned long long mm0 = m0, mm1 = m1;
        while (pi | (mm0 != 0ull) | (mm1 != 0ull)) {
            int rA, rB;
            bool hasB = false;
            if (pi) { rA = i2; pi = false; }
            else if (mm0) { int t = __ffsll(mm0) - 1; rA = 2 * t; mm0 &= mm0 - 1; }
            else { int t = __ffsll(mm1) - 1; rA = 2 * t + 1; mm1 &= mm1 - 1; }
            if (mm0) { int t = __ffsll(mm0) - 1; rB = 2 * t; mm0 &= mm0 - 1; hasB = true; }
            else if (mm1) { int t = __ffsll(mm1) - 1; rB = 2 * t + 1; mm1 &= mm1 - 1; hasB = true; }
            else rB = rA;

            int r = (lane < 32) ? rA : rB;
            int h = lane & 31;
            int L = 127 - r;
            int base = pidx(r, r + 1);
            float bv = INFINITY;
            int bj = 127;
            for (int t = h; t < L; t += 32) {
                float v = cost[base + t];
                if (v < bv) { bv = v; bj = r + 1 + t; }
            }
            unsigned long long key = half_min64(mkkey(bv, r, bj));
            unsigned long long keyA = read64(key, 31);
            unsigned long long keyB = read64(key, 63);
            if (lane == (rA >> 1)) { if (rA & 1) k1 = keyA; else k0 = keyA; }
            if (hasB && lane == (rB >> 1)) { if (rB & 1) k1 = keyB; else k0 = keyB; }
        }
        wbar();
    }

    // final relabel: survivors -> 0..K-1 by index order
    szsE[r0] = s0;
    szsE[r1] = s1;
    wbar();
    if (lane == 0) {
        int c = 0;
        for (int i = 0; i < NPTS; ++i) rnk[i] = (szsE[i] > 0.f) ? c++ : -1;
    }
    wbar();
    out[b * NPTS + r0] = rnk[lab0];
    out[b * NPTS + r1] = rnk[lab1];
}

extern "C" void kernel_launch(void* const* d_in, const int* in_sizes, int n_in,
                              void* d_out, int out_size, void* d_ws, size_t ws_size,
                              hipStream_t stream) {
    const float* x  = (const float*)d_in[0];
    const float* W1 = (const float*)d_in[1];
    const float* b1 = (const float*)d_in[2];
    const float* W2 = (const float*)d_in[3];
    const float* b2 = (const float*)d_in[4];

    float* h = (float*)d_ws;                       // 16384*256 f32 = 16 MB
    float* feats = h + (size_t)MROWS * H1;         // 16384*32 f32 = 2 MB
    int* out = (int*)d_out;

    mlp1_kernel<<<dim3(MROWS / 128, 2), 256, 0, stream>>>(x, W1, b1, h);
    mlp2_kernel<<<MROWS / 16, 256, 0, stream>>>(h, W2, b2, feats);
    ward_kernel<<<BB, 256, 0, stream>>>(feats, out);
}

// Round 4
// 487.063 us; speedup vs baseline: 1.6209x; 1.2575x over previous
//
#include <hip/hip_runtime.h>
#include <math.h>

#define BB 128
#define NN 128
#define DIN 1024
#define H1 256
#define DOUT 32
#define KCL 8
#define NPTS 128
#define MROWS (BB*NN)   // 16384
#define CSTR 130        // centsT row stride (words)
#define RSTR 132        // cost row stride (words, 16B aligned)
#define DEADKEY 0xFFFFFFFF00000000ull

__device__ __forceinline__ float gelu_exact(float v) {
    return 0.5f * v * (1.0f + erff(v * 0.70710678118654752f));
}

__device__ __forceinline__ unsigned long long mkkey(float v, int r, int j) {
    // key = (f32 bits << 32) | flat index r*128+j  -> lex min == jnp.argmin over full matrix
    return ((unsigned long long)__float_as_uint(v) << 32) | (unsigned)((r << 7) | j);
}

template<int CTRL, int RMASK>
__device__ __forceinline__ unsigned long long dpp_min_step(unsigned long long k) {
    unsigned lo = (unsigned)k, hi = (unsigned)(k >> 32);
    unsigned tlo = (unsigned)__builtin_amdgcn_update_dpp((int)lo, (int)lo, CTRL, RMASK, 0xf, false);
    unsigned thi = (unsigned)__builtin_amdgcn_update_dpp((int)hi, (int)hi, CTRL, RMASK, 0xf, false);
    unsigned long long t = ((unsigned long long)thi << 32) | tlo;
    return t < k ? t : k;
}

__device__ __forceinline__ unsigned long long read64(unsigned long long k, int lane) {
    unsigned lo = (unsigned)__builtin_amdgcn_readlane((int)(unsigned)k, lane);
    unsigned hi = (unsigned)__builtin_amdgcn_readlane((int)(k >> 32), lane);
    return ((unsigned long long)hi << 32) | lo;
}

__device__ __forceinline__ unsigned long long wave_min64(unsigned long long k) {
    k = dpp_min_step<0x111, 0xf>(k);
    k = dpp_min_step<0x112, 0xf>(k);
    k = dpp_min_step<0x114, 0xf>(k);
    k = dpp_min_step<0x118, 0xf>(k);
    k = dpp_min_step<0x142, 0xa>(k);
    k = dpp_min_step<0x143, 0xc>(k);
    return read64(k, 63);
}

// dual 32-lane min: lane31 = min(lanes0..31), lane63 = min(lanes32..63)
__device__ __forceinline__ unsigned long long half_min64(unsigned long long k) {
    k = dpp_min_step<0x111, 0xf>(k);
    k = dpp_min_step<0x112, 0xf>(k);
    k = dpp_min_step<0x114, 0xf>(k);
    k = dpp_min_step<0x118, 0xf>(k);
    k = dpp_min_step<0x142, 0xa>(k);
    return k;
}

// ---------------- GEMM1: h = gelu(x) @ W1 + b1 ; 64x64 tile, BK=32, 4 blocks/CU ----------------
__global__ __launch_bounds__(256) void mlp1_kernel(const float* __restrict__ x,
                                                   const float* __restrict__ W1,
                                                   const float* __restrict__ b1,
                                                   float* __restrict__ h) {
    __shared__ float As[32][68];  // [k][m]
    __shared__ float Bs[32][68];  // [k][n]
    const int bm = blockIdx.x;    // 256 row-tiles of 64
    const int bn = blockIdx.y;    // 4 col-tiles of 64
    const int tid = threadIdx.x;
    const int tx = tid & 15, ty = tid >> 4;

    float acc[4][4] = {{0.f}};

    const int arow = tid >> 2;         // 0..63
    const int acol4 = (tid & 3) * 4;   // k offset 0,4,8,12
    const int brow = tid >> 4;         // 0..15 (k)
    const int bcol4 = (tid & 15) * 4;  // 0..60

    const float* xrow = x + (size_t)(bm * 64 + arow) * DIN;
    const float* wbase = W1 + bn * 64;

    for (int kt = 0; kt < DIN; kt += 32) {
        float4 a0 = *(const float4*)(xrow + kt + acol4);
        float4 a1 = *(const float4*)(xrow + kt + 16 + acol4);
        float4 w0 = *(const float4*)(wbase + (size_t)(kt + brow) * H1 + bcol4);
        float4 w1 = *(const float4*)(wbase + (size_t)(kt + 16 + brow) * H1 + bcol4);
        __syncthreads();
        As[acol4 + 0][arow] = gelu_exact(a0.x);
        As[acol4 + 1][arow] = gelu_exact(a0.y);
        As[acol4 + 2][arow] = gelu_exact(a0.z);
        As[acol4 + 3][arow] = gelu_exact(a0.w);
        As[16 + acol4 + 0][arow] = gelu_exact(a1.x);
        As[16 + acol4 + 1][arow] = gelu_exact(a1.y);
        As[16 + acol4 + 2][arow] = gelu_exact(a1.z);
        As[16 + acol4 + 3][arow] = gelu_exact(a1.w);
        *(float4*)&Bs[brow][bcol4] = w0;
        *(float4*)&Bs[16 + brow][bcol4] = w1;
        __syncthreads();
#pragma unroll
        for (int kk = 0; kk < 32; ++kk) {
            float4 a = *(const float4*)&As[kk][ty * 4];
            float4 b = *(const float4*)&Bs[kk][tx * 4];
            float ar[4] = {a.x, a.y, a.z, a.w};
            float br[4] = {b.x, b.y, b.z, b.w};
#pragma unroll
            for (int i = 0; i < 4; ++i)
#pragma unroll
                for (int j = 0; j < 4; ++j)
                    acc[i][j] = fmaf(ar[i], br[j], acc[i][j]);
        }
    }

    const int row = bm * 64 + ty * 4;
    const int col = bn * 64 + tx * 4;
    float4 bias = *(const float4*)(b1 + col);
#pragma unroll
    for (int i = 0; i < 4; ++i) {
        float4 o;
        o.x = acc[i][0] + bias.x;
        o.y = acc[i][1] + bias.y;
        o.z = acc[i][2] + bias.z;
        o.w = acc[i][3] + bias.w;
        *(float4*)(h + (size_t)(row + i) * H1 + col) = o;
    }
}

// ---------------- GEMM2: feats = gelu(h) @ W2 + b2 ----------------
__global__ __launch_bounds__(256) void mlp2_kernel(const float* __restrict__ h,
                                                   const float* __restrict__ W2,
                                                   const float* __restrict__ b2,
                                                   float* __restrict__ feats) {
    __shared__ float hs[16][257];
    __shared__ float w2s[H1 * DOUT];
    const int blk = blockIdx.x;
    const int tid = threadIdx.x;

    for (int i = tid; i < (H1 * DOUT) / 4; i += 256) {
        ((float4*)w2s)[i] = ((const float4*)W2)[i];
    }
    const float* hb = h + (size_t)blk * 16 * H1;
    for (int i = tid; i < (16 * H1) / 4; i += 256) {
        float4 v = ((const float4*)hb)[i];
        int r = i >> 6;
        int c = (i & 63) * 4;
        hs[r][c + 0] = gelu_exact(v.x);
        hs[r][c + 1] = gelu_exact(v.y);
        hs[r][c + 2] = gelu_exact(v.z);
        hs[r][c + 3] = gelu_exact(v.w);
    }
    __syncthreads();

    const int col = tid & 31;
    const int r0 = (tid >> 5) * 2;
    float acc0 = 0.f, acc1 = 0.f;
    for (int k = 0; k < H1; ++k) {
        float w = w2s[k * DOUT + col];
        acc0 = fmaf(hs[r0 + 0][k], w, acc0);
        acc1 = fmaf(hs[r0 + 1][k], w, acc1);
    }
    float bias = b2[col];
    const int rowg = blk * 16 + r0;
    feats[(size_t)(rowg + 0) * DOUT + col] = acc0 + bias;
    feats[(size_t)(rowg + 1) * DOUT + col] = acc1 + bias;
}

// ---------------- Ward clustering: full-matrix cost, register transpose, single wave ----------------
__global__ __launch_bounds__(256) void ward_kernel(const float* __restrict__ feats,
                                                   int* __restrict__ out) {
    __shared__ __align__(16) float cost[NPTS * RSTR];  // 67.6 KB full matrix
    __shared__ float centsT[32 * CSTR];                // [d][r], 16.6 KB
    __shared__ unsigned long long rowkey[NPTS];
    __shared__ float sqArr[NPTS];
    __shared__ float szsE[NPTS];
    __shared__ int rnk[NPTS];

    const int b = blockIdx.x;
    const int tid = threadIdx.x;
    const float* f = feats + (size_t)b * NPTS * DOUT;
    const float INF = __builtin_inff();

    // ---- init (all 4 waves) ----
    for (int i = tid; i < NPTS * DOUT; i += 256) {
        int r = i >> 5, d = i & 31;
        centsT[d * CSTR + r] = f[i];
    }
    __syncthreads();
    if (tid < NPTS) {
        float s = 0.f;
#pragma unroll
        for (int d = 0; d < 32; ++d) {
            float v = centsT[d * CSTR + tid];
            s = fmaf(v, v, s);
        }
        sqArr[tid] = s;
    }
    __syncthreads();
    // full Gram: 256 threads = 16x16 tiles of 8x8
    {
        int ti = tid >> 4, tj = tid & 15;
        int I0 = ti * 8, J0 = tj * 8;
        float acc[8][8];
#pragma unroll
        for (int u = 0; u < 8; ++u)
#pragma unroll
            for (int v = 0; v < 8; ++v) acc[u][v] = 0.f;
        for (int d = 0; d < 32; ++d) {
            float a[8], bb[8];
#pragma unroll
            for (int u = 0; u < 8; ++u) a[u] = centsT[d * CSTR + I0 + u];
#pragma unroll
            for (int v = 0; v < 8; ++v) bb[v] = centsT[d * CSTR + J0 + v];
#pragma unroll
            for (int u = 0; u < 8; ++u)
#pragma unroll
                for (int v = 0; v < 8; ++v)
                    acc[u][v] = fmaf(a[u], bb[v], acc[u][v]);
        }
#pragma unroll
        for (int u = 0; u < 8; ++u) {
#pragma unroll
            for (int v = 0; v < 8; ++v) {
                int i = I0 + u, j = J0 + v;
                float d2 = sqArr[i] + sqArr[j] - 2.0f * acc[u][v];
                if (d2 < 0.f) d2 = 0.f;
                float w = (1.0f * 1.0f) / (1.0f + 1.0f + 1e-30f);
                cost[i * RSTR + j] = (i == j) ? INF : w * d2;
            }
        }
    }
    __syncthreads();
    // initial rowkeys: exact per-row argmin (first-index tie-break via lex key)
    if (tid < NPTS) {
        unsigned long long best = DEADKEY;
        for (int j = 0; j < NPTS; ++j) {
            float v = cost[tid * RSTR + j];
            unsigned long long k = mkkey(v, tid, j);
            if (k < best) best = k;
        }
        rowkey[tid] = best;
    }
    __syncthreads();

    if (tid >= 64) return;  // wave 0 only from here
    const int lane = tid;
    const int r0 = lane * 2, r1 = lane * 2 + 1;

    unsigned long long k0 = rowkey[r0], k1 = rowkey[r1];
    float q0 = sqArr[r0], q1 = sqArr[r1];
    float s0 = 1.0f, s1 = 1.0f;
    int lab0 = r0, lab1 = r1;

    for (int it = 0; it < NPTS - KCL; ++it) {
        // P1: global argmin = min over exact row argmins
        unsigned long long kmin = k0 < k1 ? k0 : k1;
        kmin = wave_min64(kmin);
        const int ra = (int)((kmin >> 7) & 127u);
        const int ca = (int)(kmin & 127u);
        const int i2 = ra < ca ? ra : ca;
        const int j2 = ra < ca ? ca : ra;

        float candi = (i2 & 1) ? s1 : s0;
        float candj = (j2 & 1) ? s1 : s0;
        float si = __int_as_float(__builtin_amdgcn_readlane(__float_as_int(candi), i2 >> 1));
        float sj = __int_as_float(__builtin_amdgcn_readlane(__float_as_int(candj), j2 >> 1));
        const float snew = si + sj;

        int arg0 = (int)(k0 & 127u), arg1 = (int)(k1 & 127u);
        bool d0 = (s0 > 0.f) && r0 != i2 && r0 != j2 && (arg0 == i2 || arg0 == j2);
        bool d1 = (s1 > 0.f) && r1 != i2 && r1 != j2 && (arg1 == i2 || arg1 == j2);
        unsigned long long m0 = __ballot(d0), m1 = __ballot(d1);

        // P3: merge centroid (lanes<32 hold dim d = lane)
        float newc = 0.f;
        if (lane < 32) {
            float ci = centsT[lane * CSTR + i2];
            float cj = centsT[lane * CSTR + j2];
            newc = (ci * si + cj * sj) / (si + sj);
            centsT[lane * CSTR + i2] = newc;
        }
        // kill column j2 (row j2 is never scanned again)
        cost[r0 * RSTR + j2] = INF;
        cost[r1 * RSTR + j2] = INF;
        if (lab0 == j2) lab0 = i2;
        if (lab1 == j2) lab1 = i2;
        if (r0 == i2) s0 = snew; else if (r0 == j2) { s0 = 0.f; k0 = DEADKEY; }
        if (r1 == i2) s1 = snew; else if (r1 == j2) { s1 = 0.f; k1 = DEADKEY; }

        // register transpose: broadcast newc (lane d) to all lanes as c2[d]
        float c2[32];
#pragma unroll
        for (int d = 0; d < 32; ++d)
            c2[d] = __int_as_float(__builtin_amdgcn_readlane(__float_as_int(newc), d));

        // P4: qn + dots purely from registers (own rows via one ds_read_b64 per d)
        float qn = 0.f, dot0 = 0.f, dot1 = 0.f;
#pragma unroll
        for (int d = 0; d < 32; ++d) {
            float2 ow = *(const float2*)&centsT[d * CSTR + r0];
            qn = fmaf(c2[d], c2[d], qn);
            dot0 = fmaf(ow.x, c2[d], dot0);
            dot1 = fmaf(ow.y, c2[d], dot1);
        }
        if (r0 == i2) q0 = qn;
        if (r1 == i2) q1 = qn;
        bool w0 = (s0 > 0.f) && r0 != i2 && r0 != j2;
        bool w1 = (s1 > 0.f) && r1 != i2 && r1 != j2;
        unsigned long long ki2 = DEADKEY;
        if (w0) {
            float d2 = q0 + qn - 2.0f * dot0;
            if (d2 < 0.f) d2 = 0.f;
            float w = (s0 * snew) / (s0 + snew + 1e-30f);
            float v0 = w * d2;
            cost[r0 * RSTR + i2] = v0;
            cost[i2 * RSTR + r0] = v0;
            if (!d0) {
                unsigned long long nk = mkkey(v0, r0, i2);
                if (nk < k0) k0 = nk;
            }
            ki2 = mkkey(v0, i2, r0);
        }
        if (w1) {
            float d2 = q1 + qn - 2.0f * dot1;
            if (d2 < 0.f) d2 = 0.f;
            float w = (s1 * snew) / (s1 + snew + 1e-30f);
            float v1 = w * d2;
            cost[r1 * RSTR + i2] = v1;
            cost[i2 * RSTR + r1] = v1;
            if (!d1) {
                unsigned long long nk = mkkey(v1, r1, i2);
                if (nk < k1) k1 = nk;
            }
            unsigned long long kk1 = mkkey(v1, i2, r1);
            if (kk1 < ki2) ki2 = kk1;
        }
        // row i2's new key: min over just-computed values (dead/self contribute DEADKEY)
        ki2 = wave_min64(ki2);
        if (r0 == i2) k0 = ki2;
        if (r1 == i2) k1 = ki2;

        // P6: dirty-row rescans, 2 rows per round, one ds_read_b128 per lane
        unsigned long long mm0 = m0, mm1 = m1;
        while (mm0 | mm1) {
            int rA, rB;
            bool hasB = false;
            if (mm0) { int t = __ffsll(mm0) - 1; rA = 2 * t; mm0 &= mm0 - 1; }
            else     { int t = __ffsll(mm1) - 1; rA = 2 * t + 1; mm1 &= mm1 - 1; }
            if (mm0) { int t = __ffsll(mm0) - 1; rB = 2 * t; mm0 &= mm0 - 1; hasB = true; }
            else if (mm1) { int t = __ffsll(mm1) - 1; rB = 2 * t + 1; mm1 &= mm1 - 1; hasB = true; }
            else rB = rA;

            int r = (lane < 32) ? rA : rB;
            int hh = lane & 31;
            float4 cv = *(const float4*)&cost[r * RSTR + 4 * hh];
            unsigned long long kk = mkkey(cv.x, r, 4 * hh + 0);
            unsigned long long t1 = mkkey(cv.y, r, 4 * hh + 1);
            unsigned long long t2 = mkkey(cv.z, r, 4 * hh + 2);
            unsigned long long t3 = mkkey(cv.w, r, 4 * hh + 3);
            if (t1 < kk) kk = t1;
            if (t2 < kk) kk = t2;
            if (t3 < kk) kk = t3;
            kk = half_min64(kk);
            unsigned long long keyA = read64(kk, 31);
            unsigned long long keyB = read64(kk, 63);
            if (lane == (rA >> 1)) { if (rA & 1) k1 = keyA; else k0 = keyA; }
            if (hasB && lane == (rB >> 1)) { if (rB & 1) k1 = keyB; else k0 = keyB; }
        }
    }

    // final relabel: survivors -> 0..K-1 by index order
    szsE[r0] = s0;
    szsE[r1] = s1;
    __asm__ volatile("s_waitcnt lgkmcnt(0)" ::: "memory");
    if (lane == 0) {
        int c = 0;
        for (int i = 0; i < NPTS; ++i) rnk[i] = (szsE[i] > 0.f) ? c++ : -1;
    }
    __asm__ volatile("s_waitcnt lgkmcnt(0)" ::: "memory");
    out[b * NPTS + r0] = rnk[lab0];
    out[b * NPTS + r1] = rnk[lab1];
}

extern "C" void kernel_launch(void* const* d_in, const int* in_sizes, int n_in,
                              void* d_out, int out_size, void* d_ws, size_t ws_size,
                              hipStream_t stream) {
    const float* x  = (const float*)d_in[0];
    const float* W1 = (const float*)d_in[1];
    const float* b1 = (const float*)d_in[2];
    const float* W2 = (const float*)d_in[3];
    const float* b2 = (const float*)d_in[4];

    float* h = (float*)d_ws;                       // 16 MB
    float* feats = h + (size_t)MROWS * H1;         // 2 MB
    int* out = (int*)d_out;

    mlp1_kernel<<<dim3(MROWS / 64, H1 / 64), 256, 0, stream>>>(x, W1, b1, h);
    mlp2_kernel<<<MROWS / 16, 256, 0, stream>>>(h, W2, b2, feats);
    ward_kernel<<<BB, 256, 0, stream>>>(feats, out);
}